// Round 10
// baseline (346.268 us; speedup 1.0000x reference)
//
#include <hip/hip_runtime.h>
#include <hip/hip_bf16.h>
#include <math.h>

#define NN 262144
#define NCC 65536

typedef __bf16 bf16x8 __attribute__((ext_vector_type(8)));
typedef __bf16 bf16x4 __attribute__((ext_vector_type(4)));
typedef float f32x4 __attribute__((ext_vector_type(4)));

// ---------- setup: blocks 0..47 precompute Mt; blocks 48..559 zero rank arrays ----------
__global__ __launch_bounds__(256) void k_setup(const float* __restrict__ w_orig,
                                               const float* __restrict__ w_prop,
                                               const float* __restrict__ w_ctx,
                                               const float* __restrict__ W_fuse,
                                               __bf16* __restrict__ Mt,
                                               int* __restrict__ ranks) {
    __shared__ float Wl[64 * 65];
    __shared__ float wl[64 * 65];
    int b = blockIdx.x;
    int t = threadIdx.x;
    if (b >= 48) {   // zero 2*NN rank ints (2 MB): 512 blocks * 256 threads * 16B
        ((uint4*)ranks)[(b - 48) * 256 + t] = make_uint4(0u, 0u, 0u, 0u);
        return;
    }
    int seg = b >> 4, rem = b & 15;
    int ot = rem >> 2, mt = rem & 3;
    const float* wseg = seg == 0 ? w_orig : (seg == 1 ? w_prop : w_ctx);
    int to = (t & 15) * 4, tm = (t >> 4) * 4;
    float acc[4][4] = {};
    for (int kc = 0; kc < 4; ++kc) {
        __syncthreads();
        for (int i = 0; i < 16; ++i) {
            int f = i * 256 + t;
            int row = f >> 6, col = f & 63;
            Wl[row * 65 + col] = W_fuse[(size_t)(ot * 64 + row) * 768 + seg * 256 + kc * 64 + col];
            wl[row * 65 + col] = wseg[(size_t)(mt * 64 + row) * 256 + kc * 64 + col];
        }
        __syncthreads();
        for (int k = 0; k < 64; ++k) {
            float wo[4], wm2[4];
#pragma unroll
            for (int i = 0; i < 4; ++i) wo[i] = Wl[(to + i) * 65 + k];
#pragma unroll
            for (int j = 0; j < 4; ++j) wm2[j] = wl[(tm + j) * 65 + k];
#pragma unroll
            for (int i = 0; i < 4; ++i)
#pragma unroll
                for (int j = 0; j < 4; ++j) acc[i][j] += wo[i] * wm2[j];
        }
    }
    for (int i = 0; i < 4; ++i)
        for (int j = 0; j < 4; ++j) {
            int o = ot * 64 + to + i;
            int g = seg * 256 + mt * 64 + tm + j;
            Mt[(size_t)o * 768 + g] = (__bf16)acc[i][j];
        }
}

__global__ void k_setrank(const int* __restrict__ idxp, const int* __restrict__ idxc,
                          int* rankp, int* rankc) {
    int j = blockIdx.x * blockDim.x + threadIdx.x;
    if (j < NCC) { rankp[idxp[j]] = j + 1; rankc[idxc[j]] = j + 1; }
}

// ---------- pass 1: stream rows; rank==0 -> copy to out, else -> bf16 compact ----------
__global__ __launch_bounds__(256) void k_pass1(const float* __restrict__ hp,
                                               const float* __restrict__ hc,
                                               const int* __restrict__ rankp,
                                               const int* __restrict__ rankc,
                                               __bf16* __restrict__ compP,
                                               __bf16* __restrict__ compC,
                                               float* __restrict__ out0,
                                               float* __restrict__ out1) {
    int bid = blockIdx.x;                 // 2048 blocks: 1024 per table, 256 rows each
    int t = threadIdx.x, lane = t & 63, wid = t >> 6;
    int tbl = bid >= 1024;
    const float* S = tbl ? hc : hp;
    const int* R = tbl ? rankc : rankp;
    float* D = tbl ? out1 : out0;
    __bf16* C = tbl ? compC : compP;
    int r0 = (tbl ? bid - 1024 : bid) * 256 + wid * 64;   // wave owns 64 consecutive rows
#pragma unroll
    for (int g = 0; g < 8; ++g) {
        int rk[8];
        f32x4 v[8];
#pragma unroll
        for (int i = 0; i < 8; ++i) rk[i] = R[r0 + g * 8 + i];
#pragma unroll
        for (int i = 0; i < 8; ++i)
            v[i] = *(const f32x4*)(S + (size_t)(r0 + g * 8 + i) * 256 + lane * 4);
#pragma unroll
        for (int i = 0; i < 8; ++i) {
            int r = r0 + g * 8 + i;
            if (rk[i] == 0) {                         // wave-uniform branch
                *(f32x4*)(D + (size_t)r * 256 + lane * 4) = v[i];
            } else {
                bf16x4 w;
                w[0] = (__bf16)v[i][0]; w[1] = (__bf16)v[i][1];
                w[2] = (__bf16)v[i][2]; w[3] = (__bf16)v[i][3];
                *(bf16x4*)(C + (size_t)(rk[i] - 1) * 256 + lane * 4) = w;
            }
        }
    }
}

#define MFMA __builtin_amdgcn_mfma_f32_16x16x32_bf16

__device__ inline bf16x8 cvt8(f32x4 a, f32x4 b) {
    bf16x8 w;
    w[0] = (__bf16)a[0]; w[1] = (__bf16)a[1]; w[2] = (__bf16)a[2]; w[3] = (__bf16)a[3];
    w[4] = (__bf16)b[0]; w[5] = (__bf16)b[1]; w[6] = (__bf16)b[2]; w[7] = (__bf16)b[3];
    return w;
}

// ---------- pass 2: dense GEMM (A: horig f32 + compact bf16), scatter epilogue ----------
__global__ __launch_bounds__(512, 4) void k_pass2(const float* __restrict__ horig,
                                                  const __bf16* __restrict__ compP,
                                                  const __bf16* __restrict__ compC,
                                                  const __bf16* __restrict__ Mt,
                                                  const float* __restrict__ bfuse,
                                                  const float* __restrict__ bias,
                                                  const int* __restrict__ idxp,
                                                  const int* __restrict__ idxc,
                                                  float* __restrict__ out0,
                                                  float* __restrict__ out1) {
    __shared__ __align__(16) char smem[40960];
    __bf16* Al = (__bf16*)smem;            // 8 KB, swizzled
    __bf16* Bl = (__bf16*)(smem + 8192);   // 32 KB, swizzled
    int t = threadIdx.x;
    int jbase = blockIdx.x * 64;
    int lane = t & 63, wid = t >> 6;
    int wm = wid >> 2, wn = wid & 3;
    int l15 = lane & 15, lq = lane >> 4;

    // A staging: thread -> (row ar, slot aslot of 8 elems)
    int ar = t >> 3, aslot = t & 7;
    const float* arow0 = horig + (size_t)(jbase + ar) * 256 + aslot * 8;
    const __bf16* arow1 = compP + (size_t)(jbase + ar) * 256 + aslot * 8;
    const __bf16* arow2 = compC + (size_t)(jbase + ar) * 256 + aslot * 8;

    // B staging: thread -> (row bo, 32-elem half bkp)
    int bo = t >> 1, bkp = t & 1;
    const __bf16* bsrc = Mt + (size_t)bo * 768 + bkp * 32;

    f32x4 acc[2][4] = {};

    // prologue: chunk 0 (seg0, f32) + B chunk 0
    f32x4 va0 = *(const f32x4*)(arow0);
    f32x4 va1 = *(const f32x4*)(arow0 + 4);
    bf16x8 vab;
    bf16x8 vb[4];
#pragma unroll
    for (int i = 0; i < 4; ++i) vb[i] = *(const bf16x8*)(bsrc + i * 8);

#pragma unroll
    for (int c = 0; c < 12; ++c) {
        __syncthreads();
        // write prefetched chunk c to LDS
        if (c < 4) *(bf16x8*)&Al[ar * 64 + ((aslot ^ (ar & 7)) << 3)] = cvt8(va0, va1);
        else       *(bf16x8*)&Al[ar * 64 + ((aslot ^ (ar & 7)) << 3)] = vab;
#pragma unroll
        for (int i = 0; i < 4; ++i) {
            int slot = bkp * 4 + i;
            *(bf16x8*)&Bl[bo * 64 + ((slot ^ (bo & 7)) << 3)] = vb[i];
        }
        // prefetch chunk c+1
        if (c < 11) {
            int cn = c + 1, ko = (cn & 3) * 64;
            if (cn < 4) {
                va0 = *(const f32x4*)(arow0 + ko);
                va1 = *(const f32x4*)(arow0 + ko + 4);
            } else if (cn < 8) {
                vab = *(const bf16x8*)(arow1 + ko);
            } else {
                vab = *(const bf16x8*)(arow2 + ko);
            }
#pragma unroll
            for (int i = 0; i < 4; ++i) vb[i] = *(const bf16x8*)(bsrc + cn * 64 + i * 8);
        }
        __syncthreads();
        // compute chunk c
#pragma unroll
        for (int ks = 0; ks < 2; ++ks) {
            bf16x8 af[2], bfr[4];
            int kslot = ks * 4 + lq;
#pragma unroll
            for (int mi = 0; mi < 2; ++mi) {
                int r = wm * 32 + mi * 16 + l15;
                af[mi] = *(const bf16x8*)&Al[r * 64 + ((kslot ^ (r & 7)) << 3)];
            }
#pragma unroll
            for (int ni = 0; ni < 4; ++ni) {
                int o = wn * 64 + ni * 16 + l15;
                bfr[ni] = *(const bf16x8*)&Bl[o * 64 + ((kslot ^ (o & 7)) << 3)];
            }
#pragma unroll
            for (int mi = 0; mi < 2; ++mi)
#pragma unroll
                for (int ni = 0; ni < 4; ++ni)
                    acc[mi][ni] = MFMA(af[mi], bfr[ni], acc[mi][ni], 0, 0, 0);
        }
    }

    // epilogue: tanh + bias, per-wave LDS transpose, f32x4 contiguous scattered stores
    float bfv[4], biv[4];
#pragma unroll
    for (int ni = 0; ni < 4; ++ni) {
        int o = wn * 64 + ni * 16 + l15;
        bfv[ni] = bfuse[o];
        biv[ni] = bias[o];
    }
    __syncthreads();   // all LDS reads done; reuse Bl region as scratch
    float* scr = (float*)(smem + 8192 + wid * 4096);   // per-wave 16x64 f32
#pragma unroll
    for (int mi = 0; mi < 2; ++mi) {
#pragma unroll
        for (int ni = 0; ni < 4; ++ni)
#pragma unroll
            for (int rr = 0; rr < 4; ++rr) {
                float v = tanhf(acc[mi][ni][rr] + bfv[ni]) + biv[ni];
                scr[(lq * 4 + rr) * 64 + ni * 16 + l15] = v;
            }
        // intra-wave ds ordering: own writes visible to own reads
#pragma unroll
        for (int rnd = 0; rnd < 4; ++rnd) {
            int rr2 = rnd * 4 + lq;
            int j = jbase + wm * 32 + mi * 16 + rr2;
            int gp = idxp[j], gc = idxc[j];
            f32x4 v = *(const f32x4*)&scr[rr2 * 64 + l15 * 4];
            *(f32x4*)(out0 + (size_t)gp * 256 + wn * 64 + l15 * 4) = v;
            *(f32x4*)(out1 + (size_t)gc * 256 + wn * 64 + l15 * 4) = v;
        }
    }
}

extern "C" void kernel_launch(void* const* d_in, const int* in_sizes, int n_in,
                              void* d_out, int out_size, void* d_ws, size_t ws_size,
                              hipStream_t stream) {
    const float* hp     = (const float*)d_in[0];
    const float* hc     = (const float*)d_in[1];
    const float* horig  = (const float*)d_in[2];
    const float* w_orig = (const float*)d_in[3];
    const float* w_prop = (const float*)d_in[4];
    const float* w_ctx  = (const float*)d_in[5];
    const float* W_fuse = (const float*)d_in[6];
    const float* bfuse  = (const float*)d_in[7];
    const float* bias   = (const float*)d_in[8];
    const int* idxp     = (const int*)d_in[9];
    const int* idxc     = (const int*)d_in[10];
    float* out0 = (float*)d_out;
    float* out1 = out0 + (size_t)NN * 256;

    char* ws = (char*)d_ws;
    __bf16* Mt  = (__bf16*)ws;                                  // 384 KB
    int* rankp  = (int*)(ws + 393216);                          // 1 MB
    int* rankc  = (int*)(ws + 393216 + 1048576);                // 1 MB
    __bf16* compP = (__bf16*)(ws + 393216 + 2097152);           // 32 MB
    __bf16* compC = (__bf16*)(ws + 393216 + 2097152 + 33554432);// 32 MB

    k_setup<<<560, 256, 0, stream>>>(w_orig, w_prop, w_ctx, W_fuse, Mt, rankp);
    k_setrank<<<NCC / 256, 256, 0, stream>>>(idxp, idxc, rankp, rankc);
    k_pass1<<<2048, 256, 0, stream>>>(hp, hc, rankp, rankc, compP, compC, out0, out1);
    k_pass2<<<NCC / 64, 512, 0, stream>>>(horig, compP, compC, Mt, bfuse, bias,
                                          idxp, idxc, out0, out1);
}